// Round 6
// baseline (384.806 us; speedup 1.0000x reference)
//
#include <hip/hip_runtime.h>

#define N_NODES 100000
#define N_EDGES 1600000
#define IN_C    64
#define HID_C   128
#define OUT_C   64
#define N_CLS   20

#define BUCKETS 196          // ceil(N_NODES / 512), 512 nodes per bucket
#define XSL     8            // one slice per XCD (blockIdx & 7)
#define WCAP    2560         // per (bucket,xcd) window; mean 1020, huge margin
#define EPB     4096         // edges per binA block
#define CAPB    44           // per-block per-bucket LDS cap; mean 20.9, +5sig

typedef __attribute__((ext_vector_type(8))) short short8;   // 8 bf16 = 4 VGPR
typedef __attribute__((ext_vector_type(4))) float floatx4;  // MFMA acc

__device__ __forceinline__ unsigned short f2bf(float f) {  // RNE
    union { float f; unsigned u; } v; v.f = f;
    unsigned r = v.u + 0x7FFFu + ((v.u >> 16) & 1u);
    return (unsigned short)(r >> 16);
}
__device__ __forceinline__ unsigned pk2(float lo, float hi) {
    return (unsigned)f2bf(lo) | ((unsigned)f2bf(hi) << 16);
}
__device__ __forceinline__ float bflo(unsigned w) { return __uint_as_float(w << 16); }
__device__ __forceinline__ float bfhi(unsigned w) { return __uint_as_float(w & 0xFFFF0000u); }

// ---- CSR build: binned counting sort (round-5 design) ---------------------
__global__ __launch_bounds__(256) void binA_kernel(
        const int* __restrict__ ei, int* __restrict__ bcnt,
        unsigned* __restrict__ bins)
{
    __shared__ unsigned lbins[BUCKETS * CAPB];
    __shared__ unsigned comp[EPB];
    __shared__ unsigned dsti[EPB];
    __shared__ int lcnt[BUCKETS], lofs[BUCKETS], gb[BUCKETS];
    __shared__ int sd[256];

    const int tid = threadIdx.x;
    const int xcd = blockIdx.x & (XSL - 1);
    const int e0  = blockIdx.x * EPB;

    for (int w = tid; w < BUCKETS; w += 256) lcnt[w] = 0;
    __syncthreads();

    for (int it = 0; it < EPB / 256; ++it) {
        int e = e0 + it * 256 + tid;
        if (e >= N_EDGES) break;
        int src = ei[e];
        int dst = ei[N_EDGES + e];
        int b = dst >> 9;
        unsigned pk = ((unsigned)(dst & 511) << 17) | (unsigned)src;
        int pos = atomicAdd(&lcnt[b], 1);
        if (pos < CAPB) {
            lbins[b * CAPB + pos] = pk;
        } else {  // rare fallback: direct global append (always correct)
            int gp = atomicAdd(&bcnt[b * XSL + xcd], 1);
            if (gp < WCAP)
                bins[(unsigned)(b * XSL + xcd) * WCAP + gp] = pk;
        }
    }
    __syncthreads();

    int c = (tid < BUCKETS) ? min(lcnt[tid], CAPB) : 0;
    sd[tid] = c;
    __syncthreads();
    for (int off = 1; off < 256; off <<= 1) {
        int x = 0;
        if (tid >= off) x = sd[tid - off];
        __syncthreads();
        if (tid >= off) sd[tid] += x;
        __syncthreads();
    }
    if (tid < BUCKETS) lofs[tid] = sd[tid] - c;
    __syncthreads();
    const int T = sd[255];

    if (tid < BUCKETS) {
        int cw = min(lcnt[tid], CAPB);
        gb[tid] = (cw > 0) ? atomicAdd(&bcnt[tid * XSL + xcd], cw) : 0;
    }
    __syncthreads();

    if (tid < BUCKETS) {
        int cw = min(lcnt[tid], CAPB);
        int lo = lofs[tid];
        unsigned wb = (unsigned)(tid * XSL + xcd) * WCAP + (unsigned)gb[tid];
        for (int i = 0; i < cw; ++i) {
            comp[lo + i] = lbins[tid * CAPB + i];
            dsti[lo + i] = wb + i;
        }
    }
    __syncthreads();

    for (int i = tid; i < T; i += 256)
        bins[dsti[i]] = comp[i];
}

__global__ __launch_bounds__(256) void bscan_kernel(
        const int* __restrict__ bcnt, int* __restrict__ bucket_base,
        int* __restrict__ row_ptr)
{
    __shared__ int sd[256];
    int t = threadIdx.x;
    int tot = 0;
    if (t < BUCKETS) {
        for (int sl = 0; sl < XSL; ++sl)
            tot += min(bcnt[t * XSL + sl], WCAP);
    }
    sd[t] = tot;
    __syncthreads();
    for (int off = 1; off < 256; off <<= 1) {
        int x = 0;
        if (t >= off) x = sd[t - off];
        __syncthreads();
        if (t >= off) sd[t] += x;
        __syncthreads();
    }
    if (t < BUCKETS) bucket_base[t] = sd[t] - tot;
    if (t == 0) row_ptr[N_NODES] = N_EDGES;
}

__global__ __launch_bounds__(256) void buildB_kernel(
        const int* __restrict__ bcnt, const unsigned* __restrict__ bins,
        const int* __restrict__ bucket_base,
        int* __restrict__ row_ptr, int* __restrict__ sorted_src,
        float* __restrict__ dinv)
{
    __shared__ unsigned ent[16384];
    __shared__ int scnt[XSL], soff[XSL];
    __shared__ int cnt[512], lofs[512], cur[512];
    __shared__ int sd[256];

    const int b   = blockIdx.x;
    const int tid = threadIdx.x;
    const int node0 = b * 512;

    if (tid < XSL) scnt[tid] = min(bcnt[b * XSL + tid], WCAP);
    { int i = tid; cnt[i] = 0; cnt[i + 256] = 0; }
    __syncthreads();
    if (tid == 0) {
        int acc = 0;
        for (int sl = 0; sl < XSL; ++sl) {
            soff[sl] = acc;
            acc += scnt[sl];
            if (acc > 16384) { scnt[sl] -= (acc - 16384); acc = 16384; } // unreachable
        }
    }
    __syncthreads();

    for (int sl = 0; sl < XSL; ++sl) {
        int len = scnt[sl];
        const unsigned* seg = bins + (unsigned)(b * XSL + sl) * WCAP;
        int base = soff[sl];
        for (int i = tid; i < len; i += 256) {
            unsigned e = seg[i];
            ent[base + i] = e;
            atomicAdd((unsigned*)&cnt[e >> 17], 1u);
        }
    }
    __syncthreads();
    const int T = soff[XSL - 1] + scnt[XSL - 1];

    int a0 = cnt[2 * tid], a1 = cnt[2 * tid + 1];
    int s2 = a0 + a1;
    sd[tid] = s2;
    __syncthreads();
    for (int off = 1; off < 256; off <<= 1) {
        int x = 0;
        if (tid >= off) x = sd[tid - off];
        __syncthreads();
        if (tid >= off) sd[tid] += x;
        __syncthreads();
    }
    int excl = sd[tid] - s2;
    lofs[2 * tid]     = excl;
    lofs[2 * tid + 1] = excl + a0;
    cur[2 * tid]      = excl;
    cur[2 * tid + 1]  = excl + a0;
    __syncthreads();

    const int gbase = bucket_base[b];
    for (int j = tid; j < 512; j += 256) {
        int node = node0 + j;
        if (node < N_NODES) {
            row_ptr[node] = gbase + lofs[j];
            dinv[node] = 1.0f / (float)max(cnt[j], 1);
        }
    }
    for (int i = tid; i < T; i += 256) {
        unsigned e = ent[i];
        int dl = e >> 17;
        int p = atomicAdd((unsigned*)&cur[dl], 1u);
        sorted_src[gbase + p] = (int)(e & 0x1FFFFu);
    }
}

// ---- conversions ----------------------------------------------------------
// xb is SLAB-MAJOR: [8 slabs][N][8 ch] bf16; slab s holds channels [8s, 8s+8).
__global__ __launch_bounds__(256) void cvt_x_kernel(
        const float* __restrict__ x, unsigned short* __restrict__ xb)
{
    int i = blockIdx.x * 256 + threadIdx.x;
    if (i >= N_NODES * 8) return;
    int n = i >> 3, sl = i & 7;
    float4 a = *(const float4*)(x + (size_t)n * 64 + sl * 8);
    float4 b = *(const float4*)(x + (size_t)n * 64 + sl * 8 + 4);
    uint4 r;
    r.x = pk2(a.x, a.y); r.y = pk2(a.z, a.w);
    r.z = pk2(b.x, b.y); r.w = pk2(b.z, b.w);
    ((uint4*)xb)[(size_t)sl * N_NODES + n] = r;
}

__global__ __launch_bounds__(256) void prep_wt_kernel(
        const float* __restrict__ ws1, const float* __restrict__ wn1,   // [64][128]
        const float* __restrict__ ws2, const float* __restrict__ wn2,   // [128][64]
        unsigned short* __restrict__ wt1s, unsigned short* __restrict__ wt1n, // [128][64]
        unsigned short* __restrict__ wt2s, unsigned short* __restrict__ wt2n) // [64][128]
{
    int i = blockIdx.x * 256 + threadIdx.x;
    if (i < 8192) {
        int o = i >> 6, c = i & 63;
        wt1s[i] = f2bf(ws1[c * 128 + o]);
        wt1n[i] = f2bf(wn1[c * 128 + o]);
    } else if (i < 16384) {
        int j = i - 8192;
        int o = j >> 7, c = j & 127;
        wt2s[j] = f2bf(ws2[c * 64 + o]);
        wt2n[j] = f2bf(wn2[c * 64 + o]);
    }
}

// ---- gather-mean, XCD-affine channel slabs --------------------------------
// featb slab-major [8][N][8]; slab = blockIdx&7 so all readers of a slab land
// on one XCD (round-robin dispatch) -> 1.6 MB slab stays L2-resident.
// One thread per (node, slab); 4x-unrolled edge loop for MLP.
__global__ __launch_bounds__(256) void gatherb_kernel(
        const int* __restrict__ row_ptr, const int* __restrict__ srcs,
        const unsigned short* __restrict__ featb,  // [8][N][8] bf16
        const float* __restrict__ dinv,
        unsigned short* __restrict__ aggb)         // node-major [N][64] bf16
{
    const int slab = blockIdx.x & 7;
    const int n = (blockIdx.x >> 3) * 256 + threadIdx.x;
    if (n >= N_NODES) return;
    int beg = row_ptr[n];
    int end = row_ptr[n + 1];
    const uint4* f4 = (const uint4*)featb + (size_t)slab * N_NODES;
    float a0=0,a1=0,a2=0,a3=0,a4=0,a5=0,a6=0,a7=0;
    int e = beg;
    for (; e + 4 <= end; e += 4) {
        int s0 = srcs[e], s1 = srcs[e+1], s2 = srcs[e+2], s3 = srcs[e+3];
        uint4 v0 = f4[s0];
        uint4 v1 = f4[s1];
        uint4 v2 = f4[s2];
        uint4 v3 = f4[s3];
        a0 += bflo(v0.x); a1 += bfhi(v0.x); a2 += bflo(v0.y); a3 += bfhi(v0.y);
        a4 += bflo(v0.z); a5 += bfhi(v0.z); a6 += bflo(v0.w); a7 += bfhi(v0.w);
        a0 += bflo(v1.x); a1 += bfhi(v1.x); a2 += bflo(v1.y); a3 += bfhi(v1.y);
        a4 += bflo(v1.z); a5 += bfhi(v1.z); a6 += bflo(v1.w); a7 += bfhi(v1.w);
        a0 += bflo(v2.x); a1 += bfhi(v2.x); a2 += bflo(v2.y); a3 += bfhi(v2.y);
        a4 += bflo(v2.z); a5 += bfhi(v2.z); a6 += bflo(v2.w); a7 += bfhi(v2.w);
        a0 += bflo(v3.x); a1 += bfhi(v3.x); a2 += bflo(v3.y); a3 += bfhi(v3.y);
        a4 += bflo(v3.z); a5 += bfhi(v3.z); a6 += bflo(v3.w); a7 += bfhi(v3.w);
    }
    for (; e < end; ++e) {
        uint4 v = f4[srcs[e]];
        a0 += bflo(v.x); a1 += bfhi(v.x); a2 += bflo(v.y); a3 += bfhi(v.y);
        a4 += bflo(v.z); a5 += bfhi(v.z); a6 += bflo(v.w); a7 += bfhi(v.w);
    }
    float di = dinv[n];
    uint4 r;
    r.x = pk2(a0 * di, a1 * di);
    r.y = pk2(a2 * di, a3 * di);
    r.z = pk2(a4 * di, a5 * di);
    r.w = pk2(a6 * di, a7 * di);
    ((uint4*)aggb)[(size_t)n * 8 + slab] = r;
}

// ---- MFMA GEMMs (D[m=out_ch][n=node]) -------------------------------------

__global__ __launch_bounds__(256) void dense1_mfma(
        const unsigned short* __restrict__ xb,    // [8][N][8] slab-major
        const unsigned short* __restrict__ aggb,  // [N][64] node-major
        const unsigned short* __restrict__ wts,   // [128][64]
        const unsigned short* __restrict__ wtn,   // [128][64]
        const float* __restrict__ bias,           // [128]
        unsigned short* __restrict__ h1b)         // [N][128] node-major
{
    int lane = threadIdx.x & 63;
    int wv   = threadIdx.x >> 6;
    int quad = lane >> 4;
    int col  = lane & 15;
    int nl = blockIdx.x * 64 + wv * 16 + col;
    int nc = min(nl, N_NODES - 1);
    bool ok = nl < N_NODES;

    // self channels quad*8 (slab=quad) and 32+quad*8 (slab=4+quad)
    const short8 bs0 = *(const short8*)(xb + ((size_t)quad       * N_NODES + nc) * 8);
    const short8 bs1 = *(const short8*)(xb + ((size_t)(4 + quad) * N_NODES + nc) * 8);
    const short8 bn0 = *(const short8*)(aggb + (size_t)nc * 64 +      quad * 8);
    const short8 bn1 = *(const short8*)(aggb + (size_t)nc * 64 + 32 + quad * 8);

#pragma unroll
    for (int mt = 0; mt < 8; ++mt) {
        int m = mt * 16 + col;
        const short8 as0 = *(const short8*)(wts + (size_t)m * 64 +      quad * 8);
        const short8 as1 = *(const short8*)(wts + (size_t)m * 64 + 32 + quad * 8);
        const short8 an0 = *(const short8*)(wtn + (size_t)m * 64 +      quad * 8);
        const short8 an1 = *(const short8*)(wtn + (size_t)m * 64 + 32 + quad * 8);
        floatx4 acc = {0.f, 0.f, 0.f, 0.f};
        acc = __builtin_amdgcn_mfma_f32_16x16x32_bf16(as0, bs0, acc, 0, 0, 0);
        acc = __builtin_amdgcn_mfma_f32_16x16x32_bf16(as1, bs1, acc, 0, 0, 0);
        acc = __builtin_amdgcn_mfma_f32_16x16x32_bf16(an0, bn0, acc, 0, 0, 0);
        acc = __builtin_amdgcn_mfma_f32_16x16x32_bf16(an1, bn1, acc, 0, 0, 0);
        if (ok) {
            int och = mt * 16 + quad * 4;
            float4 bv = *(const float4*)(bias + och);
            ushort4 r;
            r.x = f2bf(fmaxf(acc[0] + bv.x, 0.f));
            r.y = f2bf(fmaxf(acc[1] + bv.y, 0.f));
            r.z = f2bf(fmaxf(acc[2] + bv.z, 0.f));
            r.w = f2bf(fmaxf(acc[3] + bv.w, 0.f));
            *(ushort4*)(h1b + (size_t)nl * 128 + och) = r;
        }
    }
}

// t2 = h1 @ Wn2 -> t2b SLAB-MAJOR [8][N][8] (it is gathered next)
__global__ __launch_bounds__(256) void t2_mfma(
        const unsigned short* __restrict__ h1b,  // [N][128]
        const unsigned short* __restrict__ wtn,  // [64][128]
        unsigned short* __restrict__ t2b)        // [8][N][8]
{
    int lane = threadIdx.x & 63;
    int wv   = threadIdx.x >> 6;
    int quad = lane >> 4;
    int col  = lane & 15;
    int nl = blockIdx.x * 64 + wv * 16 + col;
    int nc = min(nl, N_NODES - 1);
    bool ok = nl < N_NODES;

    short8 b[4];
#pragma unroll
    for (int kc = 0; kc < 4; ++kc)
        b[kc] = *(const short8*)(h1b + (size_t)nc * 128 + kc * 32 + quad * 8);

#pragma unroll
    for (int mt = 0; mt < 4; ++mt) {
        int m = mt * 16 + col;
        floatx4 acc = {0.f, 0.f, 0.f, 0.f};
#pragma unroll
        for (int kc = 0; kc < 4; ++kc) {
            const short8 a = *(const short8*)(wtn + (size_t)m * 128 + kc * 32 + quad * 8);
            acc = __builtin_amdgcn_mfma_f32_16x16x32_bf16(a, b[kc], acc, 0, 0, 0);
        }
        if (ok) {
            int och  = mt * 16 + quad * 4;
            int slab = och >> 3, off = och & 7;
            ushort4 r;
            r.x = f2bf(acc[0]); r.y = f2bf(acc[1]);
            r.z = f2bf(acc[2]); r.w = f2bf(acc[3]);
            *(ushort4*)(t2b + ((size_t)slab * N_NODES + nl) * 8 + off) = r;
        }
    }
}

__global__ __launch_bounds__(256) void dense2_cls_mfma(
        const unsigned short* __restrict__ h1b,   // [N][128]
        const unsigned short* __restrict__ wts,   // [64][128]
        const unsigned short* __restrict__ agg2b, // [N][64] node-major bf16
        const float* __restrict__ b2,             // [64]
        const float* __restrict__ wc,             // [64][20]
        const float* __restrict__ bc,             // [20]
        float* __restrict__ out)                  // [N][20]
{
    __shared__ float hs[64][65];
    __shared__ float wcs[64 * N_CLS];
    __shared__ float bcs[N_CLS];

    int tid = threadIdx.x;
    int lane = tid & 63;
    int wv   = tid >> 6;
    int quad = lane >> 4;
    int col  = lane & 15;
    int node0 = blockIdx.x * 64;
    int nl = node0 + wv * 16 + col;
    int nc = min(nl, N_NODES - 1);

    for (int t = tid; t < 64 * N_CLS; t += 256) wcs[t] = wc[t];
    if (tid < N_CLS) bcs[tid] = bc[tid];

    short8 b[4];
#pragma unroll
    for (int kc = 0; kc < 4; ++kc)
        b[kc] = *(const short8*)(h1b + (size_t)nc * 128 + kc * 32 + quad * 8);

#pragma unroll
    for (int mt = 0; mt < 4; ++mt) {
        int m = mt * 16 + col;
        floatx4 acc = {0.f, 0.f, 0.f, 0.f};
#pragma unroll
        for (int kc = 0; kc < 4; ++kc) {
            const short8 a = *(const short8*)(wts + (size_t)m * 128 + kc * 32 + quad * 8);
            acc = __builtin_amdgcn_mfma_f32_16x16x32_bf16(a, b[kc], acc, 0, 0, 0);
        }
        int och = mt * 16 + quad * 4;
        ushort4 au = *(const ushort4*)(agg2b + (size_t)nc * 64 + och);
        float4 bv = *(const float4*)(b2 + och);
        hs[wv * 16 + col][och + 0] = fmaxf(acc[0] + __uint_as_float((unsigned)au.x << 16) + bv.x, 0.f);
        hs[wv * 16 + col][och + 1] = fmaxf(acc[1] + __uint_as_float((unsigned)au.y << 16) + bv.y, 0.f);
        hs[wv * 16 + col][och + 2] = fmaxf(acc[2] + __uint_as_float((unsigned)au.z << 16) + bv.z, 0.f);
        hs[wv * 16 + col][och + 3] = fmaxf(acc[3] + __uint_as_float((unsigned)au.w << 16) + bv.w, 0.f);
    }
    __syncthreads();

    for (int o = tid; o < 64 * N_CLS; o += 256) {
        int n = o / N_CLS, cls = o % N_CLS;
        if (node0 + n >= N_NODES) continue;
        float s = bcs[cls];
#pragma unroll
        for (int k = 0; k < 64; ++k) s += hs[n][k] * wcs[k * N_CLS + cls];
        out[(size_t)(node0 + n) * N_CLS + cls] = s;
    }
}

// ---------------------------------------------------------------------------

extern "C" void kernel_launch(void* const* d_in, const int* in_sizes, int n_in,
                              void* d_out, int out_size, void* d_ws, size_t ws_size,
                              hipStream_t stream)
{
    const float* x        = (const float*)d_in[0];
    const int*   ei       = (const int*)  d_in[1];
    const float* w_self1  = (const float*)d_in[2];
    const float* w_neigh1 = (const float*)d_in[3];
    const float* b1       = (const float*)d_in[4];
    const float* w_self2  = (const float*)d_in[5];
    const float* w_neigh2 = (const float*)d_in[6];
    const float* b2       = (const float*)d_in[7];
    const float* wc       = (const float*)d_in[8];
    const float* bc       = (const float*)d_in[9];
    float* out = (float*)d_out;

    const size_t N = N_NODES;
    int*      bcnt    = (int*)d_ws;                       // BUCKETS*XSL
    int*      bbase   = bcnt + BUCKETS * XSL;             // 200
    int*      row_ptr = bbase + 200;                      // N+8
    unsigned* bins    = (unsigned*)(row_ptr + N + 8);     // BUCKETS*XSL*WCAP
    int*      s_src   = (int*)(bins + BUCKETS * XSL * WCAP);  // E
    float*    dinv    = (float*)(s_src + N_EDGES);        // N
    unsigned short* xb    = (unsigned short*)(dinv + N);  // [8][N][8]
    unsigned short* agg1b = xb + 64 * N;                  // [N][64]
    unsigned short* h1b   = agg1b + 64 * N;               // [N][128]
    unsigned short* t2b   = h1b + 128 * N;                // [8][N][8]
    unsigned short* agg2b = t2b + 64 * N;                 // [N][64]
    unsigned short* wt1s  = agg2b + 64 * N;               // 128x64
    unsigned short* wt1n  = wt1s + 8192;
    unsigned short* wt2s  = wt1n + 8192;                  // 64x128
    unsigned short* wt2n  = wt2s + 8192;

    hipMemsetAsync(bcnt, 0, BUCKETS * XSL * sizeof(int), stream);

    const int EB2 = (N_EDGES + EPB - 1) / EPB;     // 391
    const int GB = ((N_NODES + 255) / 256) * 8;    // 391 chunks x 8 slabs
    const int MB = (N_NODES + 63) / 64;            // 1563

    cvt_x_kernel<<<(N_NODES * 8 + 255) / 256, 256, 0, stream>>>(x, xb);
    prep_wt_kernel<<<64, 256, 0, stream>>>(w_self1, w_neigh1, w_self2, w_neigh2,
                                           wt1s, wt1n, wt2s, wt2n);

    binA_kernel<<<EB2, 256, 0, stream>>>(ei, bcnt, bins);
    bscan_kernel<<<1, 256, 0, stream>>>(bcnt, bbase, row_ptr);
    buildB_kernel<<<BUCKETS, 256, 0, stream>>>(bcnt, bins, bbase,
                                               row_ptr, s_src, dinv);

    gatherb_kernel<<<GB, 256, 0, stream>>>(row_ptr, s_src, xb, dinv, agg1b);
    dense1_mfma<<<MB, 256, 0, stream>>>(xb, agg1b, wt1s, wt1n, b1, h1b);
    t2_mfma<<<MB, 256, 0, stream>>>(h1b, wt2n, t2b);
    gatherb_kernel<<<GB, 256, 0, stream>>>(row_ptr, s_src, t2b, dinv, agg2b);
    dense2_cls_mfma<<<MB, 256, 0, stream>>>(h1b, wt2s, agg2b, b2, wc, bc, out);
}

// Round 7
// 325.735 us; speedup vs baseline: 1.1813x; 1.1813x over previous
//
#include <hip/hip_runtime.h>

#define N_NODES 100000
#define N_EDGES 1600000
#define IN_C    64
#define HID_C   128
#define OUT_C   64
#define N_CLS   20

#define BUCKETS 196          // ceil(N_NODES / 512), 512 nodes per bucket
#define XSL     8            // one slice per XCD (blockIdx & 7)
#define WCAP    2560         // per (bucket,xcd) window; mean 1020, huge margin
#define EPB     4096         // edges per binA block
#define CAPB    44           // per-block per-bucket LDS cap; mean 20.9, +5sig

typedef __attribute__((ext_vector_type(8))) short short8;   // 8 bf16 = 4 VGPR
typedef __attribute__((ext_vector_type(4))) float floatx4;  // MFMA acc

__device__ __forceinline__ unsigned short f2bf(float f) {  // RNE
    union { float f; unsigned u; } v; v.f = f;
    unsigned r = v.u + 0x7FFFu + ((v.u >> 16) & 1u);
    return (unsigned short)(r >> 16);
}
__device__ __forceinline__ unsigned pk2(float lo, float hi) {
    return (unsigned)f2bf(lo) | ((unsigned)f2bf(hi) << 16);
}
__device__ __forceinline__ float bflo(unsigned w) { return __uint_as_float(w << 16); }
__device__ __forceinline__ float bfhi(unsigned w) { return __uint_as_float(w & 0xFFFF0000u); }

// ---- CSR build: binned counting sort (round-5 design) ---------------------
__global__ __launch_bounds__(256) void binA_kernel(
        const int* __restrict__ ei, int* __restrict__ bcnt,
        unsigned* __restrict__ bins)
{
    __shared__ unsigned lbins[BUCKETS * CAPB];
    __shared__ unsigned comp[EPB];
    __shared__ unsigned dsti[EPB];
    __shared__ int lcnt[BUCKETS], lofs[BUCKETS], gb[BUCKETS];
    __shared__ int sd[256];

    const int tid = threadIdx.x;
    const int xcd = blockIdx.x & (XSL - 1);
    const int e0  = blockIdx.x * EPB;

    for (int w = tid; w < BUCKETS; w += 256) lcnt[w] = 0;
    __syncthreads();

    for (int it = 0; it < EPB / 256; ++it) {
        int e = e0 + it * 256 + tid;
        if (e >= N_EDGES) break;
        int src = ei[e];
        int dst = ei[N_EDGES + e];
        int b = dst >> 9;
        unsigned pk = ((unsigned)(dst & 511) << 17) | (unsigned)src;
        int pos = atomicAdd(&lcnt[b], 1);
        if (pos < CAPB) {
            lbins[b * CAPB + pos] = pk;
        } else {  // rare fallback: direct global append (always correct)
            int gp = atomicAdd(&bcnt[b * XSL + xcd], 1);
            if (gp < WCAP)
                bins[(unsigned)(b * XSL + xcd) * WCAP + gp] = pk;
        }
    }
    __syncthreads();

    int c = (tid < BUCKETS) ? min(lcnt[tid], CAPB) : 0;
    sd[tid] = c;
    __syncthreads();
    for (int off = 1; off < 256; off <<= 1) {
        int x = 0;
        if (tid >= off) x = sd[tid - off];
        __syncthreads();
        if (tid >= off) sd[tid] += x;
        __syncthreads();
    }
    if (tid < BUCKETS) lofs[tid] = sd[tid] - c;
    __syncthreads();
    const int T = sd[255];

    if (tid < BUCKETS) {
        int cw = min(lcnt[tid], CAPB);
        gb[tid] = (cw > 0) ? atomicAdd(&bcnt[tid * XSL + xcd], cw) : 0;
    }
    __syncthreads();

    if (tid < BUCKETS) {
        int cw = min(lcnt[tid], CAPB);
        int lo = lofs[tid];
        unsigned wb = (unsigned)(tid * XSL + xcd) * WCAP + (unsigned)gb[tid];
        for (int i = 0; i < cw; ++i) {
            comp[lo + i] = lbins[tid * CAPB + i];
            dsti[lo + i] = wb + i;
        }
    }
    __syncthreads();

    for (int i = tid; i < T; i += 256)
        bins[dsti[i]] = comp[i];
}

__global__ __launch_bounds__(256) void bscan_kernel(
        const int* __restrict__ bcnt, int* __restrict__ bucket_base,
        int* __restrict__ row_ptr)
{
    __shared__ int sd[256];
    int t = threadIdx.x;
    int tot = 0;
    if (t < BUCKETS) {
        for (int sl = 0; sl < XSL; ++sl)
            tot += min(bcnt[t * XSL + sl], WCAP);
    }
    sd[t] = tot;
    __syncthreads();
    for (int off = 1; off < 256; off <<= 1) {
        int x = 0;
        if (t >= off) x = sd[t - off];
        __syncthreads();
        if (t >= off) sd[t] += x;
        __syncthreads();
    }
    if (t < BUCKETS) bucket_base[t] = sd[t] - tot;
    if (t == 0) row_ptr[N_NODES] = N_EDGES;
}

__global__ __launch_bounds__(256) void buildB_kernel(
        const int* __restrict__ bcnt, const unsigned* __restrict__ bins,
        const int* __restrict__ bucket_base,
        int* __restrict__ row_ptr, int* __restrict__ sorted_src,
        float* __restrict__ dinv)
{
    __shared__ unsigned ent[16384];
    __shared__ int scnt[XSL], soff[XSL];
    __shared__ int cnt[512], lofs[512], cur[512];
    __shared__ int sd[256];

    const int b   = blockIdx.x;
    const int tid = threadIdx.x;
    const int node0 = b * 512;

    if (tid < XSL) scnt[tid] = min(bcnt[b * XSL + tid], WCAP);
    { int i = tid; cnt[i] = 0; cnt[i + 256] = 0; }
    __syncthreads();
    if (tid == 0) {
        int acc = 0;
        for (int sl = 0; sl < XSL; ++sl) {
            soff[sl] = acc;
            acc += scnt[sl];
            if (acc > 16384) { scnt[sl] -= (acc - 16384); acc = 16384; } // unreachable
        }
    }
    __syncthreads();

    for (int sl = 0; sl < XSL; ++sl) {
        int len = scnt[sl];
        const unsigned* seg = bins + (unsigned)(b * XSL + sl) * WCAP;
        int base = soff[sl];
        for (int i = tid; i < len; i += 256) {
            unsigned e = seg[i];
            ent[base + i] = e;
            atomicAdd((unsigned*)&cnt[e >> 17], 1u);
        }
    }
    __syncthreads();
    const int T = soff[XSL - 1] + scnt[XSL - 1];

    int a0 = cnt[2 * tid], a1 = cnt[2 * tid + 1];
    int s2 = a0 + a1;
    sd[tid] = s2;
    __syncthreads();
    for (int off = 1; off < 256; off <<= 1) {
        int x = 0;
        if (tid >= off) x = sd[tid - off];
        __syncthreads();
        if (tid >= off) sd[tid] += x;
        __syncthreads();
    }
    int excl = sd[tid] - s2;
    lofs[2 * tid]     = excl;
    lofs[2 * tid + 1] = excl + a0;
    cur[2 * tid]      = excl;
    cur[2 * tid + 1]  = excl + a0;
    __syncthreads();

    const int gbase = bucket_base[b];
    for (int j = tid; j < 512; j += 256) {
        int node = node0 + j;
        if (node < N_NODES) {
            row_ptr[node] = gbase + lofs[j];
            dinv[node] = 1.0f / (float)max(cnt[j], 1);
        }
    }
    for (int i = tid; i < T; i += 256) {
        unsigned e = ent[i];
        int dl = e >> 17;
        int p = atomicAdd((unsigned*)&cur[dl], 1u);
        sorted_src[gbase + p] = (int)(e & 0x1FFFFu);
    }
}

// ---- conversions ----------------------------------------------------------

// x [N,64] fp32 -> bf16 node-major; one thread per 8 elements
__global__ __launch_bounds__(256) void cvt_x_kernel(
        const float* __restrict__ x, unsigned short* __restrict__ xb)
{
    int i = blockIdx.x * 256 + threadIdx.x;
    if (i >= N_NODES * 64 / 8) return;
    float4 a = ((const float4*)x)[(size_t)i * 2];
    float4 b = ((const float4*)x)[(size_t)i * 2 + 1];
    uint4 r;
    r.x = pk2(a.x, a.y); r.y = pk2(a.z, a.w);
    r.z = pk2(b.x, b.y); r.w = pk2(b.z, b.w);
    ((uint4*)xb)[i] = r;
}

__global__ __launch_bounds__(256) void prep_wt_kernel(
        const float* __restrict__ ws1, const float* __restrict__ wn1,   // [64][128]
        const float* __restrict__ ws2, const float* __restrict__ wn2,   // [128][64]
        unsigned short* __restrict__ wt1s, unsigned short* __restrict__ wt1n, // [128][64]
        unsigned short* __restrict__ wt2s, unsigned short* __restrict__ wt2n) // [64][128]
{
    int i = blockIdx.x * 256 + threadIdx.x;
    if (i < 8192) {
        int o = i >> 6, c = i & 63;
        wt1s[i] = f2bf(ws1[c * 128 + o]);
        wt1n[i] = f2bf(wn1[c * 128 + o]);
    } else if (i < 16384) {
        int j = i - 8192;
        int o = j >> 7, c = j & 127;
        wt2s[j] = f2bf(ws2[c * 64 + o]);
        wt2n[j] = f2bf(wn2[c * 64 + o]);
    }
}

// ---- gather-mean over bf16 rows of 64 channels ---------------------------
// 8 threads/node (16B each, 128B contiguous per node per edge), 4x-unrolled
// edge loop: 4 independent feature loads in flight per thread (MLP).
__global__ __launch_bounds__(256) void gatherb_kernel(
        const int* __restrict__ row_ptr, const int* __restrict__ srcs,
        const unsigned short* __restrict__ featb,  // [N][64] bf16
        const float* __restrict__ dinv, unsigned short* __restrict__ aggb)
{
    int gid = blockIdx.x * 256 + threadIdx.x;
    int n = gid >> 3;
    int q = gid & 7;
    if (n >= N_NODES) return;
    int beg = row_ptr[n];
    int end = row_ptr[n + 1];
    const uint4* f4 = (const uint4*)featb;
    float a0=0,a1=0,a2=0,a3=0,a4=0,a5=0,a6=0,a7=0;
    int e = beg;
    for (; e + 4 <= end; e += 4) {
        int s0 = srcs[e], s1 = srcs[e+1], s2 = srcs[e+2], s3 = srcs[e+3];
        uint4 v0 = f4[(size_t)s0 * 8 + q];
        uint4 v1 = f4[(size_t)s1 * 8 + q];
        uint4 v2 = f4[(size_t)s2 * 8 + q];
        uint4 v3 = f4[(size_t)s3 * 8 + q];
        a0 += bflo(v0.x); a1 += bfhi(v0.x); a2 += bflo(v0.y); a3 += bfhi(v0.y);
        a4 += bflo(v0.z); a5 += bfhi(v0.z); a6 += bflo(v0.w); a7 += bfhi(v0.w);
        a0 += bflo(v1.x); a1 += bfhi(v1.x); a2 += bflo(v1.y); a3 += bfhi(v1.y);
        a4 += bflo(v1.z); a5 += bfhi(v1.z); a6 += bflo(v1.w); a7 += bfhi(v1.w);
        a0 += bflo(v2.x); a1 += bfhi(v2.x); a2 += bflo(v2.y); a3 += bfhi(v2.y);
        a4 += bflo(v2.z); a5 += bfhi(v2.z); a6 += bflo(v2.w); a7 += bfhi(v2.w);
        a0 += bflo(v3.x); a1 += bfhi(v3.x); a2 += bflo(v3.y); a3 += bfhi(v3.y);
        a4 += bflo(v3.z); a5 += bfhi(v3.z); a6 += bflo(v3.w); a7 += bfhi(v3.w);
    }
    for (; e < end; ++e) {
        uint4 v = f4[(size_t)srcs[e] * 8 + q];
        a0 += bflo(v.x); a1 += bfhi(v.x); a2 += bflo(v.y); a3 += bfhi(v.y);
        a4 += bflo(v.z); a5 += bfhi(v.z); a6 += bflo(v.w); a7 += bfhi(v.w);
    }
    float di = dinv[n];
    uint4 r;
    r.x = pk2(a0 * di, a1 * di);
    r.y = pk2(a2 * di, a3 * di);
    r.z = pk2(a4 * di, a5 * di);
    r.w = pk2(a6 * di, a7 * di);
    ((uint4*)aggb)[(size_t)n * 8 + q] = r;
}

// ---- MFMA GEMMs (D[m=out_ch][n=node]) -------------------------------------

__global__ __launch_bounds__(256) void dense1_mfma(
        const unsigned short* __restrict__ xb,    // [N][64]
        const unsigned short* __restrict__ aggb,  // [N][64]
        const unsigned short* __restrict__ wts,   // [128][64]
        const unsigned short* __restrict__ wtn,   // [128][64]
        const float* __restrict__ bias,           // [128]
        unsigned short* __restrict__ h1b)         // [N][128]
{
    int lane = threadIdx.x & 63;
    int wv   = threadIdx.x >> 6;
    int quad = lane >> 4;
    int col  = lane & 15;
    int nl = blockIdx.x * 64 + wv * 16 + col;
    int nc = min(nl, N_NODES - 1);
    bool ok = nl < N_NODES;

    const short8 bs0 = *(const short8*)(xb   + (size_t)nc * 64 +      quad * 8);
    const short8 bs1 = *(const short8*)(xb   + (size_t)nc * 64 + 32 + quad * 8);
    const short8 bn0 = *(const short8*)(aggb + (size_t)nc * 64 +      quad * 8);
    const short8 bn1 = *(const short8*)(aggb + (size_t)nc * 64 + 32 + quad * 8);

#pragma unroll
    for (int mt = 0; mt < 8; ++mt) {
        int m = mt * 16 + col;
        const short8 as0 = *(const short8*)(wts + (size_t)m * 64 +      quad * 8);
        const short8 as1 = *(const short8*)(wts + (size_t)m * 64 + 32 + quad * 8);
        const short8 an0 = *(const short8*)(wtn + (size_t)m * 64 +      quad * 8);
        const short8 an1 = *(const short8*)(wtn + (size_t)m * 64 + 32 + quad * 8);
        floatx4 acc = {0.f, 0.f, 0.f, 0.f};
        acc = __builtin_amdgcn_mfma_f32_16x16x32_bf16(as0, bs0, acc, 0, 0, 0);
        acc = __builtin_amdgcn_mfma_f32_16x16x32_bf16(as1, bs1, acc, 0, 0, 0);
        acc = __builtin_amdgcn_mfma_f32_16x16x32_bf16(an0, bn0, acc, 0, 0, 0);
        acc = __builtin_amdgcn_mfma_f32_16x16x32_bf16(an1, bn1, acc, 0, 0, 0);
        if (ok) {
            int och = mt * 16 + quad * 4;
            float4 bv = *(const float4*)(bias + och);
            ushort4 r;
            r.x = f2bf(fmaxf(acc[0] + bv.x, 0.f));
            r.y = f2bf(fmaxf(acc[1] + bv.y, 0.f));
            r.z = f2bf(fmaxf(acc[2] + bv.z, 0.f));
            r.w = f2bf(fmaxf(acc[3] + bv.w, 0.f));
            *(ushort4*)(h1b + (size_t)nl * 128 + och) = r;
        }
    }
}

__global__ __launch_bounds__(256) void t2_mfma(
        const unsigned short* __restrict__ h1b,  // [N][128]
        const unsigned short* __restrict__ wtn,  // [64][128]
        unsigned short* __restrict__ t2b)        // [N][64]
{
    int lane = threadIdx.x & 63;
    int wv   = threadIdx.x >> 6;
    int quad = lane >> 4;
    int col  = lane & 15;
    int nl = blockIdx.x * 64 + wv * 16 + col;
    int nc = min(nl, N_NODES - 1);
    bool ok = nl < N_NODES;

    short8 b[4];
#pragma unroll
    for (int kc = 0; kc < 4; ++kc)
        b[kc] = *(const short8*)(h1b + (size_t)nc * 128 + kc * 32 + quad * 8);

#pragma unroll
    for (int mt = 0; mt < 4; ++mt) {
        int m = mt * 16 + col;
        floatx4 acc = {0.f, 0.f, 0.f, 0.f};
#pragma unroll
        for (int kc = 0; kc < 4; ++kc) {
            const short8 a = *(const short8*)(wtn + (size_t)m * 128 + kc * 32 + quad * 8);
            acc = __builtin_amdgcn_mfma_f32_16x16x32_bf16(a, b[kc], acc, 0, 0, 0);
        }
        if (ok) {
            int och = mt * 16 + quad * 4;
            ushort4 r;
            r.x = f2bf(acc[0]); r.y = f2bf(acc[1]);
            r.z = f2bf(acc[2]); r.w = f2bf(acc[3]);
            *(ushort4*)(t2b + (size_t)nl * 64 + och) = r;
        }
    }
}

__global__ __launch_bounds__(256) void dense2_cls_mfma(
        const unsigned short* __restrict__ h1b,   // [N][128]
        const unsigned short* __restrict__ wts,   // [64][128]
        const unsigned short* __restrict__ agg2b, // [N][64] bf16
        const float* __restrict__ b2,             // [64]
        const float* __restrict__ wc,             // [64][20]
        const float* __restrict__ bc,             // [20]
        float* __restrict__ out)                  // [N][20]
{
    __shared__ float hs[64][65];
    __shared__ float wcs[64 * N_CLS];
    __shared__ float bcs[N_CLS];

    int tid = threadIdx.x;
    int lane = tid & 63;
    int wv   = tid >> 6;
    int quad = lane >> 4;
    int col  = lane & 15;
    int node0 = blockIdx.x * 64;
    int nl = node0 + wv * 16 + col;
    int nc = min(nl, N_NODES - 1);

    for (int t = tid; t < 64 * N_CLS; t += 256) wcs[t] = wc[t];
    if (tid < N_CLS) bcs[tid] = bc[tid];

    short8 b[4];
#pragma unroll
    for (int kc = 0; kc < 4; ++kc)
        b[kc] = *(const short8*)(h1b + (size_t)nc * 128 + kc * 32 + quad * 8);

#pragma unroll
    for (int mt = 0; mt < 4; ++mt) {
        int m = mt * 16 + col;
        floatx4 acc = {0.f, 0.f, 0.f, 0.f};
#pragma unroll
        for (int kc = 0; kc < 4; ++kc) {
            const short8 a = *(const short8*)(wts + (size_t)m * 128 + kc * 32 + quad * 8);
            acc = __builtin_amdgcn_mfma_f32_16x16x32_bf16(a, b[kc], acc, 0, 0, 0);
        }
        int och = mt * 16 + quad * 4;
        ushort4 au = *(const ushort4*)(agg2b + (size_t)nc * 64 + och);
        float4 bv = *(const float4*)(b2 + och);
        hs[wv * 16 + col][och + 0] = fmaxf(acc[0] + __uint_as_float((unsigned)au.x << 16) + bv.x, 0.f);
        hs[wv * 16 + col][och + 1] = fmaxf(acc[1] + __uint_as_float((unsigned)au.y << 16) + bv.y, 0.f);
        hs[wv * 16 + col][och + 2] = fmaxf(acc[2] + __uint_as_float((unsigned)au.z << 16) + bv.z, 0.f);
        hs[wv * 16 + col][och + 3] = fmaxf(acc[3] + __uint_as_float((unsigned)au.w << 16) + bv.w, 0.f);
    }
    __syncthreads();

    for (int o = tid; o < 64 * N_CLS; o += 256) {
        int n = o / N_CLS, cls = o % N_CLS;
        if (node0 + n >= N_NODES) continue;
        float s = bcs[cls];
#pragma unroll
        for (int k = 0; k < 64; ++k) s += hs[n][k] * wcs[k * N_CLS + cls];
        out[(size_t)(node0 + n) * N_CLS + cls] = s;
    }
}

// ---------------------------------------------------------------------------

extern "C" void kernel_launch(void* const* d_in, const int* in_sizes, int n_in,
                              void* d_out, int out_size, void* d_ws, size_t ws_size,
                              hipStream_t stream)
{
    const float* x        = (const float*)d_in[0];
    const int*   ei       = (const int*)  d_in[1];
    const float* w_self1  = (const float*)d_in[2];
    const float* w_neigh1 = (const float*)d_in[3];
    const float* b1       = (const float*)d_in[4];
    const float* w_self2  = (const float*)d_in[5];
    const float* w_neigh2 = (const float*)d_in[6];
    const float* b2       = (const float*)d_in[7];
    const float* wc       = (const float*)d_in[8];
    const float* bc       = (const float*)d_in[9];
    float* out = (float*)d_out;

    const size_t N = N_NODES;
    int*      bcnt    = (int*)d_ws;                       // BUCKETS*XSL
    int*      bbase   = bcnt + BUCKETS * XSL;             // 200
    int*      row_ptr = bbase + 200;                      // N+8
    unsigned* bins    = (unsigned*)(row_ptr + N + 8);     // BUCKETS*XSL*WCAP
    int*      s_src   = (int*)(bins + BUCKETS * XSL * WCAP);  // E
    float*    dinv    = (float*)(s_src + N_EDGES);        // N
    unsigned short* xb    = (unsigned short*)(dinv + N);  // [N][64]
    unsigned short* agg1b = xb + 64 * N;                  // [N][64]
    unsigned short* h1b   = agg1b + 64 * N;               // [N][128]
    unsigned short* t2b   = h1b + 128 * N;                // [N][64]
    unsigned short* agg2b = t2b + 64 * N;                 // [N][64]
    unsigned short* wt1s  = agg2b + 64 * N;               // 128x64
    unsigned short* wt1n  = wt1s + 8192;
    unsigned short* wt2s  = wt1n + 8192;                  // 64x128
    unsigned short* wt2n  = wt2s + 8192;

    hipMemsetAsync(bcnt, 0, BUCKETS * XSL * sizeof(int), stream);

    const int EB2 = (N_EDGES + EPB - 1) / EPB;     // 391
    const int GB = (N_NODES * 8) / 256;            // 3125
    const int MB = (N_NODES + 63) / 64;            // 1563

    cvt_x_kernel<<<(N_NODES * 64 / 8 + 255) / 256, 256, 0, stream>>>(x, xb);
    prep_wt_kernel<<<64, 256, 0, stream>>>(w_self1, w_neigh1, w_self2, w_neigh2,
                                           wt1s, wt1n, wt2s, wt2n);

    binA_kernel<<<EB2, 256, 0, stream>>>(ei, bcnt, bins);
    bscan_kernel<<<1, 256, 0, stream>>>(bcnt, bbase, row_ptr);
    buildB_kernel<<<BUCKETS, 256, 0, stream>>>(bcnt, bins, bbase,
                                               row_ptr, s_src, dinv);

    gatherb_kernel<<<GB, 256, 0, stream>>>(row_ptr, s_src, xb, dinv, agg1b);
    dense1_mfma<<<MB, 256, 0, stream>>>(xb, agg1b, wt1s, wt1n, b1, h1b);
    t2_mfma<<<MB, 256, 0, stream>>>(h1b, wt2n, t2b);
    gatherb_kernel<<<GB, 256, 0, stream>>>(row_ptr, s_src, t2b, dinv, agg2b);
    dense2_cls_mfma<<<MB, 256, 0, stream>>>(h1b, wt2s, agg2b, b2, wc, bc, out);
}

// Round 8
// 301.322 us; speedup vs baseline: 1.2771x; 1.0810x over previous
//
#include <hip/hip_runtime.h>

#define N_NODES 100000
#define N_EDGES 1600000
#define IN_C    64
#define HID_C   128
#define OUT_C   64
#define N_CLS   20

#define BUCKETS 196          // ceil(N_NODES / 512), 512 nodes per bucket
#define XSL     8            // one slice per XCD (blockIdx & 7)
#define WCAP    2560         // per (bucket,xcd) window; mean 1020, huge margin
#define EPB     4096         // edges per binA block
#define CAPB    44           // per-block per-bucket LDS cap; mean 20.9, +5sig

#define CVT_BLOCKS 3125      // N_NODES*64/8/256

typedef __attribute__((ext_vector_type(8))) short short8;   // 8 bf16 = 4 VGPR
typedef __attribute__((ext_vector_type(4))) float floatx4;  // MFMA acc

__device__ __forceinline__ unsigned short f2bf(float f) {  // RNE
    union { float f; unsigned u; } v; v.f = f;
    unsigned r = v.u + 0x7FFFu + ((v.u >> 16) & 1u);
    return (unsigned short)(r >> 16);
}
__device__ __forceinline__ unsigned pk2(float lo, float hi) {
    return (unsigned)f2bf(lo) | ((unsigned)f2bf(hi) << 16);
}
__device__ __forceinline__ float bflo(unsigned w) { return __uint_as_float(w << 16); }
__device__ __forceinline__ float bfhi(unsigned w) { return __uint_as_float(w & 0xFFFF0000u); }

// ---- prologue: cvt_x + prep_wt + zero bcnt in one launch ------------------
__global__ __launch_bounds__(256) void prologue_kernel(
        const float* __restrict__ x,
        const float* __restrict__ ws1, const float* __restrict__ wn1,
        const float* __restrict__ ws2, const float* __restrict__ wn2,
        unsigned short* __restrict__ xb,
        unsigned short* __restrict__ wt1s, unsigned short* __restrict__ wt1n,
        unsigned short* __restrict__ wt2s, unsigned short* __restrict__ wt2n,
        int* __restrict__ bcnt)
{
    const int bid = blockIdx.x, tid = threadIdx.x;
    if (bid < CVT_BLOCKS) {
        int i = bid * 256 + tid;              // < 800000 exactly
        float4 a = ((const float4*)x)[(size_t)i * 2];
        float4 b = ((const float4*)x)[(size_t)i * 2 + 1];
        uint4 r;
        r.x = pk2(a.x, a.y); r.y = pk2(a.z, a.w);
        r.z = pk2(b.x, b.y); r.w = pk2(b.z, b.w);
        ((uint4*)xb)[i] = r;
    } else if (bid == CVT_BLOCKS) {
        for (int i = tid; i < BUCKETS * XSL; i += 256) bcnt[i] = 0;
    } else {
        int i = (bid - CVT_BLOCKS - 1) * 256 + tid;
        if (i < 8192) {                       // layer 1: [128][64]
            int o = i >> 6, c = i & 63;
            wt1s[i] = f2bf(ws1[c * 128 + o]);
            wt1n[i] = f2bf(wn1[c * 128 + o]);
        } else if (i < 16384) {               // layer 2: [64][128]
            int j = i - 8192;
            int o = j >> 7, c = j & 127;
            wt2s[j] = f2bf(ws2[c * 64 + o]);
            wt2n[j] = f2bf(wn2[c * 64 + o]);
        }
    }
}

// ---- CSR build: binned counting sort --------------------------------------
__global__ __launch_bounds__(256) void binA_kernel(
        const int* __restrict__ ei, int* __restrict__ bcnt,
        unsigned* __restrict__ bins)
{
    __shared__ unsigned lbins[BUCKETS * CAPB];
    __shared__ unsigned comp[EPB];
    __shared__ unsigned dsti[EPB];
    __shared__ int lcnt[BUCKETS], lofs[BUCKETS], gb[BUCKETS];
    __shared__ int sd[256];

    const int tid = threadIdx.x;
    const int xcd = blockIdx.x & (XSL - 1);
    const int e0  = blockIdx.x * EPB;

    for (int w = tid; w < BUCKETS; w += 256) lcnt[w] = 0;
    __syncthreads();

    for (int it = 0; it < EPB / 256; ++it) {
        int e = e0 + it * 256 + tid;
        if (e >= N_EDGES) break;
        int src = ei[e];
        int dst = ei[N_EDGES + e];
        int b = dst >> 9;
        unsigned pk = ((unsigned)(dst & 511) << 17) | (unsigned)src;
        int pos = atomicAdd(&lcnt[b], 1);
        if (pos < CAPB) {
            lbins[b * CAPB + pos] = pk;
        } else {  // rare fallback: direct global append (always correct)
            int gp = atomicAdd(&bcnt[b * XSL + xcd], 1);
            if (gp < WCAP)
                bins[(unsigned)(b * XSL + xcd) * WCAP + gp] = pk;
        }
    }
    __syncthreads();

    int c = (tid < BUCKETS) ? min(lcnt[tid], CAPB) : 0;
    sd[tid] = c;
    __syncthreads();
    for (int off = 1; off < 256; off <<= 1) {
        int x = 0;
        if (tid >= off) x = sd[tid - off];
        __syncthreads();
        if (tid >= off) sd[tid] += x;
        __syncthreads();
    }
    if (tid < BUCKETS) lofs[tid] = sd[tid] - c;
    __syncthreads();
    const int T = sd[255];

    if (tid < BUCKETS) {
        int cw = min(lcnt[tid], CAPB);
        gb[tid] = (cw > 0) ? atomicAdd(&bcnt[tid * XSL + xcd], cw) : 0;
    }
    __syncthreads();

    if (tid < BUCKETS) {
        int cw = min(lcnt[tid], CAPB);
        int lo = lofs[tid];
        unsigned wb = (unsigned)(tid * XSL + xcd) * WCAP + (unsigned)gb[tid];
        for (int i = 0; i < cw; ++i) {
            comp[lo + i] = lbins[tid * CAPB + i];
            dsti[lo + i] = wb + i;
        }
    }
    __syncthreads();

    for (int i = tid; i < T; i += 256)
        bins[dsti[i]] = comp[i];
}

// buildB with self-computed bucket base (absorbs bscan)
__global__ __launch_bounds__(256) void buildB_kernel(
        const int* __restrict__ bcnt, const unsigned* __restrict__ bins,
        int* __restrict__ row_ptr, int* __restrict__ sorted_src,
        float* __restrict__ dinv)
{
    __shared__ unsigned ent[16384];
    __shared__ int scnt[XSL], soff[XSL];
    __shared__ int cnt[512], lofs[512], cur[512];
    __shared__ int sd[256];
    __shared__ int gbase_s;

    const int b   = blockIdx.x;
    const int tid = threadIdx.x;
    const int node0 = b * 512;

    // self-scan: bucket base = sum of all clamped counts of buckets < b
    int part = 0;
    for (int w = tid; w < b * XSL; w += 256) part += min(bcnt[w], WCAP);
    sd[tid] = part;
    __syncthreads();
    for (int off = 128; off > 0; off >>= 1) {
        if (tid < off) sd[tid] += sd[tid + off];
        __syncthreads();
    }
    if (tid == 0) {
        gbase_s = sd[0];
        if (b == 0) row_ptr[N_NODES] = N_EDGES;
    }
    __syncthreads();

    if (tid < XSL) scnt[tid] = min(bcnt[b * XSL + tid], WCAP);
    { int i = tid; cnt[i] = 0; cnt[i + 256] = 0; }
    __syncthreads();
    if (tid == 0) {
        int acc = 0;
        for (int sl = 0; sl < XSL; ++sl) {
            soff[sl] = acc;
            acc += scnt[sl];
            if (acc > 16384) { scnt[sl] -= (acc - 16384); acc = 16384; } // unreachable
        }
    }
    __syncthreads();

    for (int sl = 0; sl < XSL; ++sl) {
        int len = scnt[sl];
        const unsigned* seg = bins + (unsigned)(b * XSL + sl) * WCAP;
        int base = soff[sl];
        for (int i = tid; i < len; i += 256) {
            unsigned e = seg[i];
            ent[base + i] = e;
            atomicAdd((unsigned*)&cnt[e >> 17], 1u);
        }
    }
    __syncthreads();
    const int T = soff[XSL - 1] + scnt[XSL - 1];

    int a0 = cnt[2 * tid], a1 = cnt[2 * tid + 1];
    int s2 = a0 + a1;
    sd[tid] = s2;
    __syncthreads();
    for (int off = 1; off < 256; off <<= 1) {
        int x = 0;
        if (tid >= off) x = sd[tid - off];
        __syncthreads();
        if (tid >= off) sd[tid] += x;
        __syncthreads();
    }
    int excl = sd[tid] - s2;
    lofs[2 * tid]     = excl;
    lofs[2 * tid + 1] = excl + a0;
    cur[2 * tid]      = excl;
    cur[2 * tid + 1]  = excl + a0;
    __syncthreads();

    const int gbase = gbase_s;
    for (int j = tid; j < 512; j += 256) {
        int node = node0 + j;
        if (node < N_NODES) {
            row_ptr[node] = gbase + lofs[j];
            dinv[node] = 1.0f / (float)max(cnt[j], 1);
        }
    }
    for (int i = tid; i < T; i += 256) {
        unsigned e = ent[i];
        int dl = e >> 17;
        int p = atomicAdd((unsigned*)&cur[dl], 1u);
        sorted_src[gbase + p] = (int)(e & 0x1FFFFu);
    }
}

// ---- fused1: gather1(LDS) -> dense1 MFMA -> t2 MFMA -----------------------
// Per block: 64 nodes. aggL rows padded to 72 shorts (144B = 4 dwords mod 32
// shift/row -> 2-way LDS aliasing only, free). h1L rows 136 shorts (272B).
__global__ __launch_bounds__(256, 4) void fused1_kernel(
        const int* __restrict__ row_ptr, const int* __restrict__ srcs,
        const unsigned short* __restrict__ xb,    // [N][64]
        const float* __restrict__ dinv,
        const unsigned short* __restrict__ wt1s,  // [128][64]
        const unsigned short* __restrict__ wt1n,  // [128][64]
        const float* __restrict__ b1,             // [128]
        const unsigned short* __restrict__ wt2n,  // [64][128]
        unsigned short* __restrict__ h1b,         // [N][128]
        unsigned short* __restrict__ t2b)         // [N][64]
{
    __shared__ unsigned short aggL[64 * 72];
    __shared__ unsigned short h1L[64 * 136];

    const int tid = threadIdx.x;
    const int node0 = blockIdx.x * 64;

    // ---- phase A: gather mean(x[src]) -> aggL (bf16) ----
    {
        const int q  = tid & 7;
        const int np = tid >> 3;   // 0..31
        const uint4* f4 = (const uint4*)xb;
        for (int half = 0; half < 2; ++half) {
            int lrow = half * 32 + np;
            int n = node0 + lrow;
            float a0=0,a1=0,a2=0,a3=0,a4=0,a5=0,a6=0,a7=0;
            if (n < N_NODES) {
                int beg = row_ptr[n];
                int end = row_ptr[n + 1];
                int e = beg;
                for (; e + 4 <= end; e += 4) {
                    int s0 = srcs[e], s1 = srcs[e+1], s2 = srcs[e+2], s3 = srcs[e+3];
                    uint4 v0 = f4[(size_t)s0 * 8 + q];
                    uint4 v1 = f4[(size_t)s1 * 8 + q];
                    uint4 v2 = f4[(size_t)s2 * 8 + q];
                    uint4 v3 = f4[(size_t)s3 * 8 + q];
                    a0 += bflo(v0.x); a1 += bfhi(v0.x); a2 += bflo(v0.y); a3 += bfhi(v0.y);
                    a4 += bflo(v0.z); a5 += bfhi(v0.z); a6 += bflo(v0.w); a7 += bfhi(v0.w);
                    a0 += bflo(v1.x); a1 += bfhi(v1.x); a2 += bflo(v1.y); a3 += bfhi(v1.y);
                    a4 += bflo(v1.z); a5 += bfhi(v1.z); a6 += bflo(v1.w); a7 += bfhi(v1.w);
                    a0 += bflo(v2.x); a1 += bfhi(v2.x); a2 += bflo(v2.y); a3 += bfhi(v2.y);
                    a4 += bflo(v2.z); a5 += bfhi(v2.z); a6 += bflo(v2.w); a7 += bfhi(v2.w);
                    a0 += bflo(v3.x); a1 += bfhi(v3.x); a2 += bflo(v3.y); a3 += bfhi(v3.y);
                    a4 += bflo(v3.z); a5 += bfhi(v3.z); a6 += bflo(v3.w); a7 += bfhi(v3.w);
                }
                for (; e < end; ++e) {
                    uint4 v = f4[(size_t)srcs[e] * 8 + q];
                    a0 += bflo(v.x); a1 += bfhi(v.x); a2 += bflo(v.y); a3 += bfhi(v.y);
                    a4 += bflo(v.z); a5 += bfhi(v.z); a6 += bflo(v.w); a7 += bfhi(v.w);
                }
                float di = dinv[n];
                a0*=di; a1*=di; a2*=di; a3*=di; a4*=di; a5*=di; a6*=di; a7*=di;
            }
            uint4 r;
            r.x = pk2(a0, a1); r.y = pk2(a2, a3);
            r.z = pk2(a4, a5); r.w = pk2(a6, a7);
            *(uint4*)(aggL + lrow * 72 + q * 8) = r;   // 144B row pitch, 16B aligned
        }
    }
    __syncthreads();

    // ---- phase B: dense1 (h1 = relu(Ws1.x + Wn1.agg + b1)) ----
    const int lane = tid & 63;
    const int wv   = tid >> 6;
    const int quad = lane >> 4;
    const int col  = lane & 15;
    const int nrow = wv * 16 + col;          // local node 0..63
    const int nl = node0 + nrow;
    const int nc = min(nl, N_NODES - 1);
    const bool ok = nl < N_NODES;

    {
        const short8 bs0 = *(const short8*)(xb + (size_t)nc * 64 +      quad * 8);
        const short8 bs1 = *(const short8*)(xb + (size_t)nc * 64 + 32 + quad * 8);
        const short8 bn0 = *(const short8*)(aggL + nrow * 72 +      quad * 8);
        const short8 bn1 = *(const short8*)(aggL + nrow * 72 + 32 + quad * 8);

#pragma unroll
        for (int mt = 0; mt < 8; ++mt) {
            int m = mt * 16 + col;
            const short8 as0 = *(const short8*)(wt1s + (size_t)m * 64 +      quad * 8);
            const short8 as1 = *(const short8*)(wt1s + (size_t)m * 64 + 32 + quad * 8);
            const short8 an0 = *(const short8*)(wt1n + (size_t)m * 64 +      quad * 8);
            const short8 an1 = *(const short8*)(wt1n + (size_t)m * 64 + 32 + quad * 8);
            floatx4 acc = {0.f, 0.f, 0.f, 0.f};
            acc = __builtin_amdgcn_mfma_f32_16x16x32_bf16(as0, bs0, acc, 0, 0, 0);
            acc = __builtin_amdgcn_mfma_f32_16x16x32_bf16(as1, bs1, acc, 0, 0, 0);
            acc = __builtin_amdgcn_mfma_f32_16x16x32_bf16(an0, bn0, acc, 0, 0, 0);
            acc = __builtin_amdgcn_mfma_f32_16x16x32_bf16(an1, bn1, acc, 0, 0, 0);
            int och = mt * 16 + quad * 4;
            float4 bv = *(const float4*)(b1 + och);
            ushort4 r;
            r.x = f2bf(fmaxf(acc[0] + bv.x, 0.f));
            r.y = f2bf(fmaxf(acc[1] + bv.y, 0.f));
            r.z = f2bf(fmaxf(acc[2] + bv.z, 0.f));
            r.w = f2bf(fmaxf(acc[3] + bv.w, 0.f));
            *(ushort4*)(h1L + nrow * 136 + och) = r;            // LDS copy for t2
            if (ok) *(ushort4*)(h1b + (size_t)nl * 128 + och) = r;
        }
    }
    __syncthreads();

    // ---- phase C: t2 = h1 @ Wn2 ----
    {
        short8 bfr[4];
#pragma unroll
        for (int kc = 0; kc < 4; ++kc)
            bfr[kc] = *(const short8*)(h1L + nrow * 136 + kc * 32 + quad * 8);

#pragma unroll
        for (int mt = 0; mt < 4; ++mt) {
            int m = mt * 16 + col;
            floatx4 acc = {0.f, 0.f, 0.f, 0.f};
#pragma unroll
            for (int kc = 0; kc < 4; ++kc) {
                const short8 a = *(const short8*)(wt2n + (size_t)m * 128 + kc * 32 + quad * 8);
                acc = __builtin_amdgcn_mfma_f32_16x16x32_bf16(a, bfr[kc], acc, 0, 0, 0);
            }
            if (ok) {
                int och = mt * 16 + quad * 4;
                ushort4 r;
                r.x = f2bf(acc[0]); r.y = f2bf(acc[1]);
                r.z = f2bf(acc[2]); r.w = f2bf(acc[3]);
                *(ushort4*)(t2b + (size_t)nl * 64 + och) = r;
            }
        }
    }
}

// ---- fused2: gather2(LDS fp32) -> dense2 MFMA + cls -----------------------
__global__ __launch_bounds__(256, 4) void fused2_kernel(
        const int* __restrict__ row_ptr, const int* __restrict__ srcs,
        const unsigned short* __restrict__ t2b,   // [N][64]
        const float* __restrict__ dinv,
        const unsigned short* __restrict__ h1b,   // [N][128]
        const unsigned short* __restrict__ wt2s,  // [64][128]
        const float* __restrict__ b2,             // [64]
        const float* __restrict__ wc,             // [64][20]
        const float* __restrict__ bc,             // [20]
        float* __restrict__ out)                  // [N][20]
{
    __shared__ float aggL[64 * 68];     // fp32, 272B row pitch
    __shared__ float hs[64][65];
    __shared__ float wcs[64 * N_CLS];
    __shared__ float bcs[N_CLS];

    const int tid = threadIdx.x;
    const int node0 = blockIdx.x * 64;

    for (int t = tid; t < 64 * N_CLS; t += 256) wcs[t] = wc[t];
    if (tid < N_CLS) bcs[tid] = bc[tid];

    // ---- phase A: gather mean(t2[src]) -> aggL (fp32) ----
    {
        const int q  = tid & 7;
        const int np = tid >> 3;
        const uint4* f4 = (const uint4*)t2b;
        for (int half = 0; half < 2; ++half) {
            int lrow = half * 32 + np;
            int n = node0 + lrow;
            float a0=0,a1=0,a2=0,a3=0,a4=0,a5=0,a6=0,a7=0;
            if (n < N_NODES) {
                int beg = row_ptr[n];
                int end = row_ptr[n + 1];
                int e = beg;
                for (; e + 4 <= end; e += 4) {
                    int s0 = srcs[e], s1 = srcs[e+1], s2 = srcs[e+2], s3 = srcs[e+3];
                    uint4 v0 = f4[(size_t)s0 * 8 + q];
                    uint4 v1 = f4[(size_t)s1 * 8 + q];
                    uint4 v2 = f4[(size_t)s2 * 8 + q];
                    uint4 v3 = f4[(size_t)s3 * 8 + q];
                    a0 += bflo(v0.x); a1 += bfhi(v0.x); a2 += bflo(v0.y); a3 += bfhi(v0.y);
                    a4 += bflo(v0.z); a5 += bfhi(v0.z); a6 += bflo(v0.w); a7 += bfhi(v0.w);
                    a0 += bflo(v1.x); a1 += bfhi(v1.x); a2 += bflo(v1.y); a3 += bfhi(v1.y);
                    a4 += bflo(v1.z); a5 += bfhi(v1.z); a6 += bflo(v1.w); a7 += bfhi(v1.w);
                    a0 += bflo(v2.x); a1 += bfhi(v2.x); a2 += bflo(v2.y); a3 += bfhi(v2.y);
                    a4 += bflo(v2.z); a5 += bfhi(v2.z); a6 += bflo(v2.w); a7 += bfhi(v2.w);
                    a0 += bflo(v3.x); a1 += bfhi(v3.x); a2 += bflo(v3.y); a3 += bfhi(v3.y);
                    a4 += bflo(v3.z); a5 += bfhi(v3.z); a6 += bflo(v3.w); a7 += bfhi(v3.w);
                }
                for (; e < end; ++e) {
                    uint4 v = f4[(size_t)srcs[e] * 8 + q];
                    a0 += bflo(v.x); a1 += bfhi(v.x); a2 += bflo(v.y); a3 += bfhi(v.y);
                    a4 += bflo(v.z); a5 += bfhi(v.z); a6 += bflo(v.w); a7 += bfhi(v.w);
                }
                float di = dinv[n];
                a0*=di; a1*=di; a2*=di; a3*=di; a4*=di; a5*=di; a6*=di; a7*=di;
            }
            float* d = aggL + lrow * 68 + q * 8;
            *(float4*)(d)     = make_float4(a0, a1, a2, a3);
            *(float4*)(d + 4) = make_float4(a4, a5, a6, a7);
        }
    }
    __syncthreads();

    // ---- phase B: dense2 MFMA + agg add + relu -> hs ----
    const int lane = tid & 63;
    const int wv   = tid >> 6;
    const int quad = lane >> 4;
    const int col  = lane & 15;
    const int nrow = wv * 16 + col;
    const int nl = node0 + nrow;
    const int nc = min(nl, N_NODES - 1);

    {
        short8 b[4];
#pragma unroll
        for (int kc = 0; kc < 4; ++kc)
            b[kc] = *(const short8*)(h1b + (size_t)nc * 128 + kc * 32 + quad * 8);

#pragma unroll
        for (int mt = 0; mt < 4; ++mt) {
            int m = mt * 16 + col;
            floatx4 acc = {0.f, 0.f, 0.f, 0.f};
#pragma unroll
            for (int kc = 0; kc < 4; ++kc) {
                const short8 a = *(const short8*)(wt2s + (size_t)m * 128 + kc * 32 + quad * 8);
                acc = __builtin_amdgcn_mfma_f32_16x16x32_bf16(a, b[kc], acc, 0, 0, 0);
            }
            int och = mt * 16 + quad * 4;
            float4 av = *(const float4*)(aggL + nrow * 68 + och);
            float4 bv = *(const float4*)(b2 + och);
            hs[nrow][och + 0] = fmaxf(acc[0] + av.x + bv.x, 0.f);
            hs[nrow][och + 1] = fmaxf(acc[1] + av.y + bv.y, 0.f);
            hs[nrow][och + 2] = fmaxf(acc[2] + av.z + bv.z, 0.f);
            hs[nrow][och + 3] = fmaxf(acc[3] + av.w + bv.w, 0.f);
        }
    }
    __syncthreads();

    for (int o = tid; o < 64 * N_CLS; o += 256) {
        int n = o / N_CLS, cls = o % N_CLS;
        if (node0 + n >= N_NODES) continue;
        float s = bcs[cls];
#pragma unroll
        for (int k = 0; k < 64; ++k) s += hs[n][k] * wcs[k * N_CLS + cls];
        out[(size_t)(node0 + n) * N_CLS + cls] = s;
    }
}

// ---------------------------------------------------------------------------

extern "C" void kernel_launch(void* const* d_in, const int* in_sizes, int n_in,
                              void* d_out, int out_size, void* d_ws, size_t ws_size,
                              hipStream_t stream)
{
    const float* x        = (const float*)d_in[0];
    const int*   ei       = (const int*)  d_in[1];
    const float* w_self1  = (const float*)d_in[2];
    const float* w_neigh1 = (const float*)d_in[3];
    const float* b1       = (const float*)d_in[4];
    const float* w_self2  = (const float*)d_in[5];
    const float* w_neigh2 = (const float*)d_in[6];
    const float* b2       = (const float*)d_in[7];
    const float* wc       = (const float*)d_in[8];
    const float* bc       = (const float*)d_in[9];
    float* out = (float*)d_out;

    const size_t N = N_NODES;
    int*      bcnt    = (int*)d_ws;                       // BUCKETS*XSL
    int*      row_ptr = bcnt + BUCKETS * XSL + 8;         // N+8
    unsigned* bins    = (unsigned*)(row_ptr + N + 8);     // BUCKETS*XSL*WCAP
    int*      s_src   = (int*)(bins + BUCKETS * XSL * WCAP);  // E
    float*    dinv    = (float*)(s_src + N_EDGES);        // N
    unsigned short* xb    = (unsigned short*)(dinv + N);  // [N][64]
    unsigned short* h1b   = xb + 64 * N;                  // [N][128]
    unsigned short* t2b   = h1b + 128 * N;                // [N][64]
    unsigned short* wt1s  = t2b + 64 * N;                 // 128x64
    unsigned short* wt1n  = wt1s + 8192;
    unsigned short* wt2s  = wt1n + 8192;                  // 64x128
    unsigned short* wt2n  = wt2s + 8192;

    const int PB  = CVT_BLOCKS + 1 + 64;           // prologue blocks
    const int EB2 = (N_EDGES + EPB - 1) / EPB;     // 391
    const int MB  = (N_NODES + 63) / 64;           // 1563

    prologue_kernel<<<PB, 256, 0, stream>>>(x, w_self1, w_neigh1, w_self2,
                                            w_neigh2, xb, wt1s, wt1n, wt2s,
                                            wt2n, bcnt);
    binA_kernel<<<EB2, 256, 0, stream>>>(ei, bcnt, bins);
    buildB_kernel<<<BUCKETS, 256, 0, stream>>>(bcnt, bins, row_ptr, s_src, dinv);
    fused1_kernel<<<MB, 256, 0, stream>>>(row_ptr, s_src, xb, dinv,
                                          wt1s, wt1n, b1, wt2n, h1b, t2b);
    fused2_kernel<<<MB, 256, 0, stream>>>(row_ptr, s_src, t2b, dinv,
                                          h1b, wt2s, b2, wc, bc, out);
}